// Round 5
// baseline (16.103 us; speedup 1.0000x reference)
//
#include <hip/hip_runtime.h>

// EmbeddingShardV2: out[b,s,:] = W[x[b,s],:] + bias
// x: [4,2048] int32, W: [50304,1024] f32, b: [1024] f32, out: [4,2048,1024] f32
//
// R1/R2: ILP structure neutral (15.84 us both). R4: NT stores 15.84->14.14 us
// (output stream no longer evicts cache). R5 probe: NT loads for W as well --
// the harness's repeated 805 MB fills between timed replays flush the 256 MB
// L3, so allocating W lines on the read path may be pure overhead. If this
// regresses, W was L3-resident after all -> revert and declare roofline.

typedef float f32x4 __attribute__((ext_vector_type(4)));

constexpr int D4  = 1024 / 4;  // float4s per row = 256
constexpr int TPB = 4;         // tokens per block

__global__ __launch_bounds__(256)
void embed_gather_ntl_kernel(const int* __restrict__ x,
                             const f32x4* __restrict__ W,
                             const f32x4* __restrict__ bias,
                             f32x4* __restrict__ out,
                             int n_tok) {
    const int t0 = blockIdx.x * TPB;
    const int i  = threadIdx.x;          // 0..255 == D4

    int r0 = x[t0 + 0];
    int r1 = x[t0 + 1];
    int r2 = x[t0 + 2];
    int r3 = x[t0 + 3];

    f32x4 bb = bias[i];

    f32x4 w0 = __builtin_nontemporal_load(&W[(size_t)r0 * D4 + i]);
    f32x4 w1 = __builtin_nontemporal_load(&W[(size_t)r1 * D4 + i]);
    f32x4 w2 = __builtin_nontemporal_load(&W[(size_t)r2 * D4 + i]);
    f32x4 w3 = __builtin_nontemporal_load(&W[(size_t)r3 * D4 + i]);

    w0 += bb;
    w1 += bb;
    w2 += bb;
    w3 += bb;

    f32x4* __restrict__ dst = out + (size_t)t0 * D4 + i;
    __builtin_nontemporal_store(w0, &dst[0 * D4]);
    __builtin_nontemporal_store(w1, &dst[1 * D4]);
    __builtin_nontemporal_store(w2, &dst[2 * D4]);
    __builtin_nontemporal_store(w3, &dst[3 * D4]);
}

extern "C" void kernel_launch(void* const* d_in, const int* in_sizes, int n_in,
                              void* d_out, int out_size, void* d_ws, size_t ws_size,
                              hipStream_t stream) {
    const int*   x    = (const int*)d_in[0];     // [B*S] = 8192
    const f32x4* W    = (const f32x4*)d_in[1];   // [50304,1024] f32
    const f32x4* bias = (const f32x4*)d_in[2];   // [1024] f32
    f32x4*       out  = (f32x4*)d_out;           // [B*S,1024] f32

    const int n_tok = in_sizes[0];               // 8192 (multiple of TPB)
    embed_gather_ntl_kernel<<<n_tok / TPB, 256, 0, stream>>>(x, W, bias, out, n_tok);
}

// Round 6
// 14.398 us; speedup vs baseline: 1.1184x; 1.1184x over previous
//
#include <hip/hip_runtime.h>

// EmbeddingShardV2: out[b,s,:] = W[x[b,s],:] + bias
// x: [4,2048] int32, W: [50304,1024] f32, b: [1024] f32, out: [4,2048,1024] f32
//
// Final config (R4 revert): regular (cached) loads for W + non-temporal
// stores for out.
//   R1/R2: ILP structure neutral (15.84 us both) -> not latency-bound.
//   R4: NT stores 15.84 -> 14.14 us (write-once output no longer evicts W).
//   R5: NT loads regressed to 16.10 us -> W reuse through L2/L3 is real;
//       keep cached loads.
// Remaining gap vs 6.3 TB/s copy ceiling = random 4KB row-gather granularity
// + launch overhead; ILP (R2) and cache policy (R5) levers both falsified.

typedef float f32x4 __attribute__((ext_vector_type(4)));

constexpr int D4  = 1024 / 4;  // float4s per row = 256
constexpr int TPB = 4;         // tokens per block

__global__ __launch_bounds__(256)
void embed_gather_nt_kernel(const int* __restrict__ x,
                            const f32x4* __restrict__ W,
                            const f32x4* __restrict__ bias,
                            f32x4* __restrict__ out,
                            int n_tok) {
    const int t0 = blockIdx.x * TPB;
    const int i  = threadIdx.x;          // 0..255 == D4

    int r0 = x[t0 + 0];
    int r1 = x[t0 + 1];
    int r2 = x[t0 + 2];
    int r3 = x[t0 + 3];

    f32x4 bb = bias[i];

    f32x4 w0 = W[(size_t)r0 * D4 + i];
    f32x4 w1 = W[(size_t)r1 * D4 + i];
    f32x4 w2 = W[(size_t)r2 * D4 + i];
    f32x4 w3 = W[(size_t)r3 * D4 + i];

    w0 += bb;
    w1 += bb;
    w2 += bb;
    w3 += bb;

    f32x4* __restrict__ dst = out + (size_t)t0 * D4 + i;
    __builtin_nontemporal_store(w0, &dst[0 * D4]);
    __builtin_nontemporal_store(w1, &dst[1 * D4]);
    __builtin_nontemporal_store(w2, &dst[2 * D4]);
    __builtin_nontemporal_store(w3, &dst[3 * D4]);
}

extern "C" void kernel_launch(void* const* d_in, const int* in_sizes, int n_in,
                              void* d_out, int out_size, void* d_ws, size_t ws_size,
                              hipStream_t stream) {
    const int*   x    = (const int*)d_in[0];     // [B*S] = 8192
    const f32x4* W    = (const f32x4*)d_in[1];   // [50304,1024] f32
    const f32x4* bias = (const f32x4*)d_in[2];   // [1024] f32
    f32x4*       out  = (f32x4*)d_out;           // [B*S,1024] f32

    const int n_tok = in_sizes[0];               // 8192 (multiple of TPB)
    embed_gather_nt_kernel<<<n_tok / TPB, 256, 0, stream>>>(x, W, bias, out, n_tok);
}